// Round 2
// baseline (529.189 us; speedup 1.0000x reference)
//
#include <hip/hip_runtime.h>

#define L_DIM 4096
#define C_DIM 256
#define B_DIM 4
#define NH 8
#define DK 32

// Folds softmax 1/sqrt(DK) AND log2(e) into Q at projection time, so the
// attention kernel uses a single v_exp_f32 (exp2) per score.
#define QSCALE 0.25507694f   // (1/sqrt(32)) * log2(e)

typedef __bf16 bf16x8 __attribute__((ext_vector_type(8)));
typedef float  f32x4  __attribute__((ext_vector_type(4)));

// ---------------------------------------------------------------------------
// Kernel 1: Q/K/V projections, no LDS: W rows are wave-uniform -> SGPR loads.
// Each block: 256 l-positions, one of {Q,K,V}, a PAIR of heads (64 channels).
// Q,K stored [B,H,L,DK] bf16 (Q pre-scaled by QSCALE); V stored [B,H,DK,L].
// ---------------------------------------------------------------------------
__global__ __launch_bounds__(256) void proj_qkv_kernel(
    const float* __restrict__ x, const float* __restrict__ Wq,
    const float* __restrict__ Wk, const float* __restrict__ Wv,
    __bf16* __restrict__ Qb, __bf16* __restrict__ Kb, __bf16* __restrict__ Vb)
{
    const int t  = threadIdx.x;
    const int l0 = blockIdx.x * 256;
    const int hp = blockIdx.y & 3;     // head pair: heads hp*2, hp*2+1
    const int p  = blockIdx.y >> 2;    // 0=Q 1=K 2=V
    const int b  = blockIdx.z;
    const float* W = (p == 0) ? Wq : ((p == 1) ? Wk : Wv);
    const float* Wrow = W + (size_t)(hp * 64) * 256;   // 64 out-channels

    float acc[64];
    #pragma unroll
    for (int o = 0; o < 64; ++o) acc[o] = 0.f;

    const float* xp = x + (size_t)b * C_DIM * L_DIM + l0 + t;

    for (int cc = 0; cc < 256; cc += 32) {
        float xv[32];
        #pragma unroll
        for (int i = 0; i < 32; ++i) xv[i] = xp[(size_t)(cc + i) * L_DIM];
        #pragma unroll
        for (int o = 0; o < 64; ++o) {
            const float* wr = Wrow + o * 256 + cc;   // uniform -> s_load
            #pragma unroll
            for (int i = 0; i < 32; ++i) acc[o] += xv[i] * wr[i];
        }
    }

    if (p < 2) {
        __bf16* out = (p == 0) ? Qb : Kb;
        const float sc = (p == 0) ? QSCALE : 1.0f;
        #pragma unroll
        for (int hh = 0; hh < 2; ++hh) {
            __bf16* op = out + ((size_t)(b*NH + hp*2 + hh) * L_DIM + l0 + t) * DK;
            #pragma unroll
            for (int k2 = 0; k2 < 4; ++k2) {
                bf16x8 pk;
                #pragma unroll
                for (int j = 0; j < 8; ++j)
                    pk[j] = (__bf16)(acc[hh*32 + k2*8 + j] * sc);
                *(bf16x8*)(op + k2*8) = pk;
            }
        }
    } else {
        #pragma unroll
        for (int hh = 0; hh < 2; ++hh)
            #pragma unroll
            for (int o = 0; o < 32; ++o)
                Vb[((size_t)(b*NH + hp*2 + hh) * DK + o) * L_DIM + l0 + t] =
                    (__bf16)acc[hh*32 + o];
    }
}

// ---------------------------------------------------------------------------
// Kernel 2: flash attention, S^T formulation.
//   S^T = K·Q^T  (D-layout gives 4 consecutive kpos per reg quad -> b64 P-store)
//   O^T = V^T·P^T (A=vfrag, B=pfrag; O^T lands directly in [d][l] order)
//   row-sums via ones-MFMA accumulated in C operand (zero per-iter VALU)
// Each wave owns 32 q rows (2 q-tiles); block = 128 q rows.
// ---------------------------------------------------------------------------
__global__ __launch_bounds__(256) void attn_kernel(
    const __bf16* __restrict__ Q, const __bf16* __restrict__ K,
    const __bf16* __restrict__ V, __bf16* __restrict__ Att)
{
    const int tid  = threadIdx.x;
    const int wave = tid >> 6;
    const int lane = tid & 63;
    const int m    = lane & 15;
    const int quad = lane >> 4;
    const int h    = blockIdx.y;
    const int b    = blockIdx.z;
    const int bh   = b * NH + h;
    const int q0   = blockIdx.x * 128 + wave * 32;   // this wave's 32 q rows

    __shared__ __attribute__((aligned(16))) __bf16 Ks[64][40];    // [kpos][dk]
    __shared__ __attribute__((aligned(16))) __bf16 Vs[32][72];    // [dk][kpos]
    __shared__ __attribute__((aligned(16))) __bf16 Ps[4][16][72]; // per wave [q][kpos]

    __bf16* Pw = &Ps[wave][0][0];

    bf16x8 qfrag[2];   // B-operand: lane n=m holds Q[q0+qt*16+m][quad*8..+8]
    qfrag[0] = *(const bf16x8*)(Q + ((size_t)bh*L_DIM + q0 +      m) * DK + quad*8);
    qfrag[1] = *(const bf16x8*)(Q + ((size_t)bh*L_DIM + q0 + 16 + m) * DK + quad*8);

    f32x4 oacc[2][2];   // [qt][dtile]: O^T[dt*16+quad*4+r][q=m]
    f32x4 lacc[2];      // [qt]: row-sum (all regs equal), col q=m
    #pragma unroll
    for (int qt = 0; qt < 2; ++qt) {
        lacc[qt] = (f32x4){0.f, 0.f, 0.f, 0.f};
        #pragma unroll
        for (int dt = 0; dt < 2; ++dt) oacc[qt][dt] = (f32x4){0.f, 0.f, 0.f, 0.f};
    }

    bf16x8 ones;
    #pragma unroll
    for (int j = 0; j < 8; ++j) ones[j] = (__bf16)1.0f;

    const __bf16* kg = K + (size_t)bh * L_DIM * DK + (tid>>2)*DK + (tid&3)*8;
    const __bf16* vg = V + ((size_t)bh * DK + (tid>>3)) * L_DIM + (tid&7)*8;
    __bf16* ksd = &Ks[tid>>2][(tid&3)*8];
    __bf16* vsd = &Vs[tid>>3][(tid&7)*8];

    bf16x8 kreg = *(const bf16x8*)kg;
    bf16x8 vreg = *(const bf16x8*)vg;

    for (int kt = 0; kt < L_DIM/64; ++kt) {
        __syncthreads();                 // prev iter's LDS reads done
        *(bf16x8*)ksd = kreg;
        *(bf16x8*)vsd = vreg;
        if (kt < L_DIM/64 - 1) {         // prefetch next tile during compute
            kreg = *(const bf16x8*)(kg + (size_t)(kt+1)*64*DK);
            vreg = *(const bf16x8*)(vg + (kt+1)*64);
        }
        __syncthreads();

        bf16x8 kf[4];                    // A-operand: A[m=kpos][k=dk]
        #pragma unroll
        for (int nt = 0; nt < 4; ++nt)
            kf[nt] = *(const bf16x8*)&Ks[nt*16 + m][quad*8];

        bf16x8 vf[2][2];                 // A-operand: A[m=d][k=kpos]
        #pragma unroll
        for (int ks = 0; ks < 2; ++ks) {
            vf[ks][0] = *(const bf16x8*)&Vs[m     ][ks*32 + quad*8];
            vf[ks][1] = *(const bf16x8*)&Vs[16 + m][ks*32 + quad*8];
        }

        #pragma unroll
        for (int qt = 0; qt < 2; ++qt) {
            // S^T[kpos][q]: 4 n-tiles of 16 kpos, single K-step (DK=32)
            f32x4 s[4];
            #pragma unroll
            for (int nt = 0; nt < 4; ++nt) {
                f32x4 z = {0.f, 0.f, 0.f, 0.f};
                s[nt] = __builtin_amdgcn_mfma_f32_16x16x32_bf16(kf[nt], qfrag[qt], z, 0, 0, 0);
            }
            // exp2 (Q pre-scaled) + pack 4 consecutive kpos -> one ds_write_b64
            #pragma unroll
            for (int nt = 0; nt < 4; ++nt) {
                union { __bf16 h4[4]; unsigned u[2]; } pk;
                #pragma unroll
                for (int r = 0; r < 4; ++r)
                    pk.h4[r] = (__bf16)__builtin_amdgcn_exp2f(s[nt][r]);
                // P[q=m][kpos = nt*16 + quad*4 + r]  (8B aligned)
                *(uint2*)&Pw[m*72 + nt*16 + quad*4] = *(uint2*)pk.u;
            }
            // O^T += V^T·P^T ; lsum += 1·P^T (per-wave LDS, in-order DS pipe)
            #pragma unroll
            for (int ks = 0; ks < 2; ++ks) {
                bf16x8 pf = *(const bf16x8*)&Pw[m*72 + ks*32 + quad*8];
                oacc[qt][0] = __builtin_amdgcn_mfma_f32_16x16x32_bf16(vf[ks][0], pf, oacc[qt][0], 0, 0, 0);
                oacc[qt][1] = __builtin_amdgcn_mfma_f32_16x16x32_bf16(vf[ks][1], pf, oacc[qt][1], 0, 0, 0);
                lacc[qt]    = __builtin_amdgcn_mfma_f32_16x16x32_bf16(ones,      pf, lacc[qt],    0, 0, 0);
            }
        }
    }

    // epilogue: normalize, relu, store — O^T already in [d][l] order
    #pragma unroll
    for (int qt = 0; qt < 2; ++qt) {
        const float inv = __builtin_amdgcn_rcpf(lacc[qt][0]);
        #pragma unroll
        for (int dt = 0; dt < 2; ++dt) {
            #pragma unroll
            for (int r = 0; r < 4; ++r) {
                float v = oacc[qt][dt][r] * inv;
                v = v > 0.f ? v : 0.f;
                const int ch = h*32 + dt*16 + quad*4 + r;
                Att[((size_t)b*C_DIM + ch) * L_DIM + q0 + qt*16 + m] = (__bf16)v;
            }
        }
    }
}

// ---------------------------------------------------------------------------
// Kernel 3: y[b,o,l] = sum_c Wl[o,c]·att[b,c,l].  No LDS: W via SGPR loads,
// stores are naturally coalesced per output channel.
// ---------------------------------------------------------------------------
__global__ __launch_bounds__(256) void final_proj_kernel(
    const __bf16* __restrict__ att, const float* __restrict__ Wl,
    float* __restrict__ y)
{
    const int t  = threadIdx.x;
    const int l0 = blockIdx.x * 256;
    const int og = blockIdx.y;          // group of 32 output channels
    const int b  = blockIdx.z;
    const float* Wrow = Wl + (size_t)(og * 32) * 256;

    float acc[32];
    #pragma unroll
    for (int o = 0; o < 32; ++o) acc[o] = 0.f;

    const __bf16* ap = att + (size_t)b * C_DIM * L_DIM + l0 + t;

    for (int cc = 0; cc < 256; cc += 32) {
        float av[32];
        #pragma unroll
        for (int i = 0; i < 32; ++i) av[i] = (float)ap[(size_t)(cc + i) * L_DIM];
        #pragma unroll
        for (int o = 0; o < 32; ++o) {
            const float* wr = Wrow + o * 256 + cc;   // uniform -> s_load
            #pragma unroll
            for (int i = 0; i < 32; ++i) acc[o] += av[i] * wr[i];
        }
    }

    #pragma unroll
    for (int o = 0; o < 32; ++o)
        y[((size_t)b*C_DIM + og*32 + o) * L_DIM + l0 + t] = acc[o];
}

// ---------------------------------------------------------------------------
extern "C" void kernel_launch(void* const* d_in, const int* in_sizes, int n_in,
                              void* d_out, int out_size, void* d_ws, size_t ws_size,
                              hipStream_t stream)
{
    const float* x  = (const float*)d_in[0];
    const float* Wq = (const float*)d_in[1];
    const float* Wk = (const float*)d_in[2];
    const float* Wv = (const float*)d_in[3];
    const float* Wl = (const float*)d_in[4];
    float* y = (float*)d_out;

    const size_t n = (size_t)B_DIM * NH * L_DIM * DK;   // 4,194,304 elems
    __bf16* Qb = (__bf16*)d_ws;
    __bf16* Kb = Qb + n;
    __bf16* Vb = Kb + n;
    __bf16* Ab = Vb + n;   // att [B,C,L]

    proj_qkv_kernel<<<dim3(L_DIM/256, 12, B_DIM), 256, 0, stream>>>(
        x, Wq, Wk, Wv, Qb, Kb, Vb);
    attn_kernel<<<dim3(L_DIM/128, NH, B_DIM), 256, 0, stream>>>(Qb, Kb, Vb, Ab);
    final_proj_kernel<<<dim3(L_DIM/256, C_DIM/32, B_DIM), 256, 0, stream>>>(Ab, Wl, y);
}

// Round 3
// 289.493 us; speedup vs baseline: 1.8280x; 1.8280x over previous
//
#include <hip/hip_runtime.h>

#define L_DIM 4096
#define C_DIM 256
#define B_DIM 4
#define NH 8
#define DK 32

// Folds softmax 1/sqrt(DK) AND log2(e) into Q at projection time, so the
// attention kernel uses a single v_exp_f32 (exp2) per score.
#define QSCALE 0.25507694f   // (1/sqrt(32)) * log2(e)

typedef __bf16 bf16x8 __attribute__((ext_vector_type(8)));
typedef float  f32x4  __attribute__((ext_vector_type(4)));

// ---------------------------------------------------------------------------
// Kernel 1: Q/K/V projections as register-blocked fp32 GEMM.
// Block: 128 out-channels x 128 l.  Thread: 8o x 8l = 64 acc.
// W transposed into LDS [c][o]; x staged [c][l]; 32-c chunks, prefetched.
// Q,K stored [B,H,L,DK] bf16 (Q pre-scaled); V stored [B,H,DK,L] bf16.
// ---------------------------------------------------------------------------
__global__ __launch_bounds__(256) void proj_qkv_kernel(
    const float* __restrict__ x, const float* __restrict__ Wq,
    const float* __restrict__ Wk, const float* __restrict__ Wv,
    __bf16* __restrict__ Qb, __bf16* __restrict__ Kb, __bf16* __restrict__ Vb)
{
    const int t   = threadIdx.x;
    const int col = t & 15;          // l-block: 8 l each
    const int row = t >> 4;          // o-block: 8 o each
    const int l0  = blockIdx.x * 128;
    const int ob  = blockIdx.y & 1;  // 128-channel half
    const int p   = blockIdx.y >> 1; // 0=Q 1=K 2=V
    const int b   = blockIdx.z;
    const float* W = (p == 0) ? Wq : ((p == 1) ? Wk : Wv);

    __shared__ __attribute__((aligned(16))) float Ws[32][132]; // [c][o]
    __shared__ __attribute__((aligned(16))) float Xs[32][132]; // [c][l]

    // staging thread mapping
    const int xc = t >> 3, xl = (t & 7) * 16;          // x: 32c x 128l
    const int wo = t >> 1, wc = (t & 1) * 16;          // W: 128o x 32c
    const float* xg = x + (size_t)b * C_DIM * L_DIM + (size_t)xc * L_DIM + l0 + xl;
    const float* wg = W + (size_t)(ob * 128 + wo) * C_DIM + wc;

    float acc[8][8];
    #pragma unroll
    for (int i = 0; i < 8; ++i)
        #pragma unroll
        for (int j = 0; j < 8; ++j) acc[i][j] = 0.f;

    f32x4 xr[4], wr[4];
    #pragma unroll
    for (int k = 0; k < 4; ++k) {
        xr[k] = *(const f32x4*)(xg + k * 4);
        wr[k] = *(const f32x4*)(wg + k * 4);
    }

    for (int ch = 0; ch < 8; ++ch) {
        __syncthreads();   // previous chunk's LDS reads done
        #pragma unroll
        for (int k = 0; k < 4; ++k) {
            *(f32x4*)&Xs[xc][xl + k * 4] = xr[k];
            #pragma unroll
            for (int u = 0; u < 4; ++u)
                Ws[wc + k * 4 + u][wo] = wr[k][u];   // transpose
        }
        if (ch < 7) {   // prefetch next chunk while this one computes
            #pragma unroll
            for (int k = 0; k < 4; ++k) {
                xr[k] = *(const f32x4*)(xg + (size_t)(ch + 1) * 32 * L_DIM + k * 4);
                wr[k] = *(const f32x4*)(wg + (ch + 1) * 32 + k * 4);
            }
        }
        __syncthreads();

        #pragma unroll 4
        for (int c = 0; c < 32; ++c) {
            const f32x4 w0 = *(const f32x4*)&Ws[c][row * 8];
            const f32x4 w1 = *(const f32x4*)&Ws[c][row * 8 + 4];
            const f32x4 x0 = *(const f32x4*)&Xs[c][col * 8];
            const f32x4 x1 = *(const f32x4*)&Xs[c][col * 8 + 4];
            #pragma unroll
            for (int i = 0; i < 4; ++i)
                #pragma unroll
                for (int j = 0; j < 4; ++j) {
                    acc[i][j]         += w0[i] * x0[j];
                    acc[i][j + 4]     += w0[i] * x1[j];
                    acc[i + 4][j]     += w1[i] * x0[j];
                    acc[i + 4][j + 4] += w1[i] * x1[j];
                }
        }
    }

    const int h      = ob * 4 + (row >> 2);
    const int dkbase = (row & 3) * 8;

    if (p < 2) {
        __bf16* out = (p == 0) ? Qb : Kb;
        const float sc = (p == 0) ? QSCALE : 1.0f;
        #pragma unroll
        for (int j = 0; j < 8; ++j) {
            const int l = l0 + col * 8 + j;
            bf16x8 pk;
            #pragma unroll
            for (int i = 0; i < 8; ++i) pk[i] = (__bf16)(acc[i][j] * sc);
            *(bf16x8*)&out[((size_t)(b * NH + h) * L_DIM + l) * DK + dkbase] = pk;
        }
    } else {
        #pragma unroll
        for (int i = 0; i < 8; ++i) {
            bf16x8 pk;
            #pragma unroll
            for (int j = 0; j < 8; ++j) pk[j] = (__bf16)acc[i][j];
            *(bf16x8*)&Vb[((size_t)(b * NH + h) * DK + dkbase + i) * L_DIM + l0 + col * 8] = pk;
        }
    }
}

// ---------------------------------------------------------------------------
// Kernel 2: flash attention, S^T formulation (unchanged from round 2).
//   S^T = K·Q^T ; O^T = V^T·P^T ; row-sums via ones-MFMA.
// Each wave owns 32 q rows (2 q-tiles); block = 128 q rows.
// ---------------------------------------------------------------------------
__global__ __launch_bounds__(256) void attn_kernel(
    const __bf16* __restrict__ Q, const __bf16* __restrict__ K,
    const __bf16* __restrict__ V, __bf16* __restrict__ Att)
{
    const int tid  = threadIdx.x;
    const int wave = tid >> 6;
    const int lane = tid & 63;
    const int m    = lane & 15;
    const int quad = lane >> 4;
    const int h    = blockIdx.y;
    const int b    = blockIdx.z;
    const int bh   = b * NH + h;
    const int q0   = blockIdx.x * 128 + wave * 32;

    __shared__ __attribute__((aligned(16))) __bf16 Ks[64][40];
    __shared__ __attribute__((aligned(16))) __bf16 Vs[32][72];
    __shared__ __attribute__((aligned(16))) __bf16 Ps[4][16][72];

    __bf16* Pw = &Ps[wave][0][0];

    bf16x8 qfrag[2];
    qfrag[0] = *(const bf16x8*)(Q + ((size_t)bh*L_DIM + q0 +      m) * DK + quad*8);
    qfrag[1] = *(const bf16x8*)(Q + ((size_t)bh*L_DIM + q0 + 16 + m) * DK + quad*8);

    f32x4 oacc[2][2];
    f32x4 lacc[2];
    #pragma unroll
    for (int qt = 0; qt < 2; ++qt) {
        lacc[qt] = (f32x4){0.f, 0.f, 0.f, 0.f};
        #pragma unroll
        for (int dt = 0; dt < 2; ++dt) oacc[qt][dt] = (f32x4){0.f, 0.f, 0.f, 0.f};
    }

    bf16x8 ones;
    #pragma unroll
    for (int j = 0; j < 8; ++j) ones[j] = (__bf16)1.0f;

    const __bf16* kg = K + (size_t)bh * L_DIM * DK + (tid>>2)*DK + (tid&3)*8;
    const __bf16* vg = V + ((size_t)bh * DK + (tid>>3)) * L_DIM + (tid&7)*8;
    __bf16* ksd = &Ks[tid>>2][(tid&3)*8];
    __bf16* vsd = &Vs[tid>>3][(tid&7)*8];

    bf16x8 kreg = *(const bf16x8*)kg;
    bf16x8 vreg = *(const bf16x8*)vg;

    for (int kt = 0; kt < L_DIM/64; ++kt) {
        __syncthreads();
        *(bf16x8*)ksd = kreg;
        *(bf16x8*)vsd = vreg;
        if (kt < L_DIM/64 - 1) {
            kreg = *(const bf16x8*)(kg + (size_t)(kt+1)*64*DK);
            vreg = *(const bf16x8*)(vg + (kt+1)*64);
        }
        __syncthreads();

        bf16x8 kf[4];
        #pragma unroll
        for (int nt = 0; nt < 4; ++nt)
            kf[nt] = *(const bf16x8*)&Ks[nt*16 + m][quad*8];

        bf16x8 vf[2][2];
        #pragma unroll
        for (int ks = 0; ks < 2; ++ks) {
            vf[ks][0] = *(const bf16x8*)&Vs[m     ][ks*32 + quad*8];
            vf[ks][1] = *(const bf16x8*)&Vs[16 + m][ks*32 + quad*8];
        }

        #pragma unroll
        for (int qt = 0; qt < 2; ++qt) {
            f32x4 s[4];
            #pragma unroll
            for (int nt = 0; nt < 4; ++nt) {
                f32x4 z = {0.f, 0.f, 0.f, 0.f};
                s[nt] = __builtin_amdgcn_mfma_f32_16x16x32_bf16(kf[nt], qfrag[qt], z, 0, 0, 0);
            }
            #pragma unroll
            for (int nt = 0; nt < 4; ++nt) {
                union { __bf16 h4[4]; unsigned u[2]; } pk;
                #pragma unroll
                for (int r = 0; r < 4; ++r)
                    pk.h4[r] = (__bf16)__builtin_amdgcn_exp2f(s[nt][r]);
                *(uint2*)&Pw[m*72 + nt*16 + quad*4] = *(uint2*)pk.u;
            }
            #pragma unroll
            for (int ks = 0; ks < 2; ++ks) {
                bf16x8 pf = *(const bf16x8*)&Pw[m*72 + ks*32 + quad*8];
                oacc[qt][0] = __builtin_amdgcn_mfma_f32_16x16x32_bf16(vf[ks][0], pf, oacc[qt][0], 0, 0, 0);
                oacc[qt][1] = __builtin_amdgcn_mfma_f32_16x16x32_bf16(vf[ks][1], pf, oacc[qt][1], 0, 0, 0);
                lacc[qt]    = __builtin_amdgcn_mfma_f32_16x16x32_bf16(ones,      pf, lacc[qt],    0, 0, 0);
            }
        }
    }

    #pragma unroll
    for (int qt = 0; qt < 2; ++qt) {
        const float inv = __builtin_amdgcn_rcpf(lacc[qt][0]);
        #pragma unroll
        for (int dt = 0; dt < 2; ++dt) {
            #pragma unroll
            for (int r = 0; r < 4; ++r) {
                float v = oacc[qt][dt][r] * inv;
                v = v > 0.f ? v : 0.f;
                const int ch = h*32 + dt*16 + quad*4 + r;
                Att[((size_t)b*C_DIM + ch) * L_DIM + q0 + qt*16 + m] = (__bf16)v;
            }
        }
    }
}

// ---------------------------------------------------------------------------
// Kernel 3: final projection, same register-blocked structure.
// att is bf16 [B,C,L]; converted to f32 at LDS-staging time.
// ---------------------------------------------------------------------------
__global__ __launch_bounds__(256) void final_proj_kernel(
    const __bf16* __restrict__ att, const float* __restrict__ Wl,
    float* __restrict__ y)
{
    const int t   = threadIdx.x;
    const int col = t & 15;
    const int row = t >> 4;
    const int l0  = blockIdx.x * 128;
    const int ob  = blockIdx.y;      // 128-channel half
    const int b   = blockIdx.z;

    __shared__ __attribute__((aligned(16))) float Ws[32][132];
    __shared__ __attribute__((aligned(16))) float Xs[32][132];

    const int xc = t >> 3, xl = (t & 7) * 16;
    const int wo = t >> 1, wc = (t & 1) * 16;
    const __bf16* ag = att + (size_t)b * C_DIM * L_DIM + (size_t)xc * L_DIM + l0 + xl;
    const float*  wg = Wl + (size_t)(ob * 128 + wo) * C_DIM + wc;

    float acc[8][8];
    #pragma unroll
    for (int i = 0; i < 8; ++i)
        #pragma unroll
        for (int j = 0; j < 8; ++j) acc[i][j] = 0.f;

    bf16x8 ar[2];
    f32x4  wr[4];
    ar[0] = *(const bf16x8*)(ag);
    ar[1] = *(const bf16x8*)(ag + 8);
    #pragma unroll
    for (int k = 0; k < 4; ++k) wr[k] = *(const f32x4*)(wg + k * 4);

    for (int ch = 0; ch < 8; ++ch) {
        __syncthreads();
        #pragma unroll
        for (int k = 0; k < 2; ++k) {
            f32x4 lo, hi;
            #pragma unroll
            for (int u = 0; u < 4; ++u) { lo[u] = (float)ar[k][u]; hi[u] = (float)ar[k][u+4]; }
            *(f32x4*)&Xs[xc][xl + k * 8]     = lo;
            *(f32x4*)&Xs[xc][xl + k * 8 + 4] = hi;
        }
        #pragma unroll
        for (int k = 0; k < 4; ++k)
            #pragma unroll
            for (int u = 0; u < 4; ++u)
                Ws[wc + k * 4 + u][wo] = wr[k][u];
        if (ch < 7) {
            ar[0] = *(const bf16x8*)(ag + (size_t)(ch + 1) * 32 * L_DIM);
            ar[1] = *(const bf16x8*)(ag + (size_t)(ch + 1) * 32 * L_DIM + 8);
            #pragma unroll
            for (int k = 0; k < 4; ++k)
                wr[k] = *(const f32x4*)(wg + (ch + 1) * 32 + k * 4);
        }
        __syncthreads();

        #pragma unroll 4
        for (int c = 0; c < 32; ++c) {
            const f32x4 w0 = *(const f32x4*)&Ws[c][row * 8];
            const f32x4 w1 = *(const f32x4*)&Ws[c][row * 8 + 4];
            const f32x4 x0 = *(const f32x4*)&Xs[c][col * 8];
            const f32x4 x1 = *(const f32x4*)&Xs[c][col * 8 + 4];
            #pragma unroll
            for (int i = 0; i < 4; ++i)
                #pragma unroll
                for (int j = 0; j < 4; ++j) {
                    acc[i][j]         += w0[i] * x0[j];
                    acc[i][j + 4]     += w0[i] * x1[j];
                    acc[i + 4][j]     += w1[i] * x0[j];
                    acc[i + 4][j + 4] += w1[i] * x1[j];
                }
        }
    }

    #pragma unroll
    for (int i = 0; i < 8; ++i) {
        const int o = ob * 128 + row * 8 + i;
        f32x4 lo, hi;
        #pragma unroll
        for (int j = 0; j < 4; ++j) { lo[j] = acc[i][j]; hi[j] = acc[i][j + 4]; }
        float* yp = y + ((size_t)b * C_DIM + o) * L_DIM + l0 + col * 8;
        *(f32x4*)yp       = lo;
        *(f32x4*)(yp + 4) = hi;
    }
}

// ---------------------------------------------------------------------------
extern "C" void kernel_launch(void* const* d_in, const int* in_sizes, int n_in,
                              void* d_out, int out_size, void* d_ws, size_t ws_size,
                              hipStream_t stream)
{
    const float* x  = (const float*)d_in[0];
    const float* Wq = (const float*)d_in[1];
    const float* Wk = (const float*)d_in[2];
    const float* Wv = (const float*)d_in[3];
    const float* Wl = (const float*)d_in[4];
    float* y = (float*)d_out;

    const size_t n = (size_t)B_DIM * NH * L_DIM * DK;   // 4,194,304 elems
    __bf16* Qb = (__bf16*)d_ws;
    __bf16* Kb = Qb + n;
    __bf16* Vb = Kb + n;
    __bf16* Ab = Vb + n;   // att [B,C,L]

    proj_qkv_kernel<<<dim3(L_DIM/128, 6, B_DIM), 256, 0, stream>>>(
        x, Wq, Wk, Wv, Qb, Kb, Vb);
    attn_kernel<<<dim3(L_DIM/128, NH, B_DIM), 256, 0, stream>>>(Qb, Kb, Vb, Ab);
    final_proj_kernel<<<dim3(L_DIM/128, 2, B_DIM), 256, 0, stream>>>(Ab, Wl, y);
}